// Round 19
// baseline (461.957 us; speedup 1.0000x reference)
//
#include <hip/hip_runtime.h>
#include <stdint.h>

// CausalMultiHeadAttention — round 12 (second resubmit; prior two benches
// were infra GPUAcquisitionTimeouts, no counters produced).
// r16 post-mortem: double-buffer NEUTRAL (356.6->361). gload16, 4 blocks/CU,
// dbuf all ~null -> GEMM is at the 128-tile structure's measured ceiling for
// this shape (17.2 GFLOP ~= 2048^3-equiv; m102 curve: 320 TF; we are at 301).
// The constant in all experiments: waves/CU = 8 (grid-limited, 2048 waves).
// This round: fuse Q/K/V projections into ONE dispatch (they share A):
// grid (64 m-tiles, 24): y<8 Q, y<16 K, else V -> 1536 blocks = 6 blocks/CU
// = 24 waves/CU (3x wave pool; m114 TLP mechanism). VGPR fits: this exact
// 256-thr codegen measured 84 VGPR in r6 (<=85 -> 6 waves/SIMD). Unlike r6's
// failed merge: which on SLOW axis (one W/out stream at a time), m on fast
// axis (XCD colocation), r9-proven epilogues/staging verbatim.
// out-GEMM (57), attn (119), to_bf16 (9): r12-measured kernels byte-identical.
// ws: Q | K | Vt (fp16) | {xb then O} (bf16) = 67.1 MB (proven size).

#define D_MODEL 1024
#define NHEAD   16
#define DK      64
#define BATCH   4
#define SEQ     2048
#define MTOT    (BATCH*SEQ)   // 8192

typedef unsigned short u16;
typedef unsigned int   u32;
typedef __bf16    bf16x8  __attribute__((ext_vector_type(8)));
typedef float     floatx4 __attribute__((ext_vector_type(4)));
typedef __fp16    fp16x2  __attribute__((ext_vector_type(2)));
typedef _Float16  half4_t __attribute__((ext_vector_type(4)));
typedef _Float16  half8_t __attribute__((ext_vector_type(8)));

// round-to-nearest-even f32 -> bf16 (epilogue only)
__device__ __forceinline__ u16 f2bf(float f){
  union { float f; u32 u; } c; c.f = f;
  u32 x = c.u;
  x += 0x7fffu + ((x >> 16) & 1u);
  return (u16)(x >> 16);
}
// f32 pair -> packed fp16 bits (RTZ, hardware packed cvt)
__device__ __forceinline__ u32 pkh(float a, float b){
  union { fp16x2 h; u32 u; } c; c.h = __builtin_amdgcn_cvt_pkrtz(a, b); return c.u;
}
// 8 fp32 -> 8 bf16 by truncation: one v_perm per pair
__device__ __forceinline__ uint4 pk8(const float* __restrict__ p){
  uint4 a = *(const uint4*)p;
  uint4 b = *(const uint4*)(p + 4);
  uint4 r;
  r.x = __builtin_amdgcn_perm(a.y, a.x, 0x07060302);
  r.y = __builtin_amdgcn_perm(a.w, a.z, 0x07060302);
  r.z = __builtin_amdgcn_perm(b.y, b.x, 0x07060302);
  r.w = __builtin_amdgcn_perm(b.w, b.z, 0x07060302);
  return r;
}
// async global->LDS, 16B per lane. LDS dest must be linear in lane order.
__device__ __forceinline__ void gload16(const void* g, void* l){
  __builtin_amdgcn_global_load_lds(
      (const __attribute__((address_space(1))) u32*)g,
      (__attribute__((address_space(3))) u32*)l, 16, 0, 0);
}

// ---------------------------------------------------------------------------
// fp32 -> bf16 trunc convert (memory-bound pre-pass for x). Exact-size grid.
// ---------------------------------------------------------------------------
__global__ __launch_bounds__(256)
void to_bf16(const float* __restrict__ s, u16* __restrict__ d)
{
  const size_t i = ((size_t)blockIdx.x * 256 + threadIdx.x) * 8;
  *(uint4*)(d + i) = pk8(s + i);
}

// ---------------------------------------------------------------------------
// Fused QKV GEMM. A (xb, bf16) via global_load_lds; W (fp32) pk8.
// 128x128 tile, BK=32, 256 thr = 4 waves in 2x2, each wave 64x64 = 4x4 MFMA.
// Grid (64 m-tiles, 24): which = y>>3 (0 Q, 1 K, 2 V — SLOW axis),
// n0 = (y&7)*128, m0 = x*128. flat%8 = x%8 -> A-tile XCD colocation.
// 1536 blocks = 6 blocks/CU = 24 waves/CU (3x the separate-launch pool).
//   which 0/1 (Q,K): mfma(W,A) -> lane=m, regs=n -> uint2 [bh][s][dk].
//   which 2  (V^T):  mfma(A,W) -> lane=n(dd), regs=m(s) -> uint2 [bh][dk][s].
// ---------------------------------------------------------------------------
__global__ __launch_bounds__(256, 3)
void gemm_qkv(const u16* __restrict__ A,
              const float* __restrict__ Wq, const float* __restrict__ bq_,
              const float* __restrict__ Wk, const float* __restrict__ bk_,
              const float* __restrict__ Wv, const float* __restrict__ bv_,
              u16* __restrict__ Qo, u16* __restrict__ Ko, u16* __restrict__ Vo)
{
  __shared__ __align__(16) u16 As[128*32];
  __shared__ __align__(16) u16 Bs[128*32];

  const int t     = threadIdx.x;
  const int m0    = blockIdx.x * 128;
  const int yy    = blockIdx.y;            // 0..23
  const int which = yy >> 3;               // 0 Q, 1 K, 2 V
  const int n0    = (yy & 7) * 128;
  const float* W    = which==0 ? Wq  : which==1 ? Wk  : Wv;
  const float* bias = which==0 ? bq_ : which==1 ? bk_ : bv_;

  const int wid = t >> 6, lane = t & 63;
  const int wr  = wid >> 1, wc = wid & 1;
  const int quad = lane >> 4, l15 = lane & 15;
  // staging chunks: c -> row = c>>2, koff = (c&3)*8 ; LDS [row][32], linear.
  const int rA0 = t >> 2, kA0 = (t & 3) * 8;   // chunk c0 = t     (rows 0..63)
  const int rA1 = rA0 + 64;                    // chunk c1 = t+256 (rows 64..127)

  floatx4 acc[4][4] = {};

  for (int k0 = 0; k0 < D_MODEL; k0 += 32) {
    __syncthreads();
    gload16(A + (size_t)(m0 + rA0)*D_MODEL + k0 + kA0, (char*)As + t*16);
    gload16(A + (size_t)(m0 + rA1)*D_MODEL + k0 + kA0, (char*)As + 4096 + t*16);
    *(uint4*)&Bs[t*8]         = pk8(W + (size_t)(n0 + rA0)*D_MODEL + k0 + kA0);
    *(uint4*)&Bs[(t + 256)*8] = pk8(W + (size_t)(n0 + rA1)*D_MODEL + k0 + kA0);
    __syncthreads();   // compiler emits vmcnt(0)+lgkmcnt(0) drain here

    bf16x8 af[4], bf[4];
#pragma unroll
    for (int i = 0; i < 4; ++i) {
      af[i] = *(const bf16x8*)&As[(wr*64 + i*16 + l15)*32 + quad*8];
      bf[i] = *(const bf16x8*)&Bs[(wc*64 + i*16 + l15)*32 + quad*8];
    }
    if (which == 2) {
#pragma unroll
      for (int mi = 0; mi < 4; ++mi)
#pragma unroll
        for (int nj = 0; nj < 4; ++nj)
          acc[mi][nj] = __builtin_amdgcn_mfma_f32_16x16x32_bf16(af[mi], bf[nj], acc[mi][nj], 0, 0, 0);
    } else {
#pragma unroll
      for (int mi = 0; mi < 4; ++mi)
#pragma unroll
        for (int nj = 0; nj < 4; ++nj)
          acc[mi][nj] = __builtin_amdgcn_mfma_f32_16x16x32_bf16(bf[nj], af[mi], acc[mi][nj], 0, 0, 0);
    }
  }

  if (which != 2) {
    // lane = m, regs = n-consecutive
    const float scale = which==0 ? 0.18033688f : 1.0f;  // 1/sqrt(dk)*log2(e)
    u16* out = which==0 ? Qo : Ko;
#pragma unroll
    for (int nj = 0; nj < 4; ++nj) {
      const int nb = n0 + wc*64 + nj*16 + quad*4;
      const float4 b4 = *(const float4*)(bias + nb);
#pragma unroll
      for (int mi = 0; mi < 4; ++mi) {
        const int m = m0 + wr*64 + mi*16 + l15;
        floatx4 d = acc[mi][nj];
        const float v0 = (d[0]+b4.x)*scale, v1 = (d[1]+b4.y)*scale;
        const float v2 = (d[2]+b4.z)*scale, v3 = (d[3]+b4.w)*scale;
        const int b = m >> 11, s = m & 2047, h = nb >> 6, dd = nb & 63;
        u16* dst = out + ((((size_t)b*NHEAD + h)*SEQ + s) << 6) + dd;
        *(uint2*)dst = make_uint2(pkh(v0, v1), pkh(v2, v3));
      }
    }
  } else {
    // lane = n (dd), regs = m (s)-consecutive
#pragma unroll
    for (int nj = 0; nj < 4; ++nj) {
      const int n  = n0 + wc*64 + nj*16 + l15;
      const float bvv = bias[n];
      const int h = n >> 6, dd = n & 63;
#pragma unroll
      for (int mi = 0; mi < 4; ++mi) {
        const int mb = m0 + wr*64 + mi*16 + quad*4;
        const int b = mb >> 11, s = mb & 2047;
        floatx4 d = acc[mi][nj];
        u16* dst = Vo + (((size_t)b*NHEAD + h)*DK + dd)*SEQ + s;
        *(uint2*)dst = make_uint2(pkh(d[0]+bvv, d[1]+bvv), pkh(d[2]+bvv, d[3]+bvv));
      }
    }
  }
}

// ---------------------------------------------------------------------------
// Output projection (r12-measured form, 57 us): A = O (bf16) via gload16,
// W = Wo fp32 pk8, fp32 [m][1024] out. 128x64 tile, 128 thr = 2 waves.
// Grid (64 m-tiles, 16 n-tiles) = 1024 blocks.
// ---------------------------------------------------------------------------
__global__ __launch_bounds__(128, 2)
void gemm_out(const u16* __restrict__ A, const float* __restrict__ W,
              const float* __restrict__ bias, float* __restrict__ outp)
{
  __shared__ __align__(16) u16 As[128*32];   // 8 KB
  __shared__ __align__(16) u16 Bs[64*32];    // 4 KB

  const int t    = threadIdx.x;              // 0..127
  const int m0   = blockIdx.x * 128;
  const int n0   = blockIdx.y * 64;
  const int wid  = t >> 6, lane = t & 63;
  const int wr   = wid;
  const int quad = lane >> 4, l15 = lane & 15;
  const int rS = t >> 2;                     // 0..31
  const int kS = (t & 3) * 8;

  floatx4 acc[4][4] = {};

  for (int k0 = 0; k0 < D_MODEL; k0 += 32) {
    __syncthreads();
    gload16(A + (size_t)(m0 + rS      )*D_MODEL + k0 + kS, (char*)As + t*16);
    gload16(A + (size_t)(m0 + rS + 32 )*D_MODEL + k0 + kS, (char*)As + 2048 + t*16);
    gload16(A + (size_t)(m0 + rS + 64 )*D_MODEL + k0 + kS, (char*)As + 4096 + t*16);
    gload16(A + (size_t)(m0 + rS + 96 )*D_MODEL + k0 + kS, (char*)As + 6144 + t*16);
    *(uint4*)&Bs[t*8]        = pk8(W + (size_t)(n0 + rS     )*D_MODEL + k0 + kS);
    *(uint4*)&Bs[t*8 + 1024] = pk8(W + (size_t)(n0 + rS + 32)*D_MODEL + k0 + kS);
    __syncthreads();

    bf16x8 af[4], bf[4];
#pragma unroll
    for (int i = 0; i < 4; ++i) {
      af[i] = *(const bf16x8*)&As[(wr*64 + i*16 + l15)*32 + quad*8];
      bf[i] = *(const bf16x8*)&Bs[(i*16 + l15)*32 + quad*8];
    }
#pragma unroll
    for (int mi = 0; mi < 4; ++mi)
#pragma unroll
      for (int nj = 0; nj < 4; ++nj)
        acc[mi][nj] = __builtin_amdgcn_mfma_f32_16x16x32_bf16(bf[nj], af[mi], acc[mi][nj], 0, 0, 0);
  }

#pragma unroll
  for (int nj = 0; nj < 4; ++nj) {
    const int nb = n0 + nj*16 + quad*4;
    const float4 b4 = *(const float4*)(bias + nb);
#pragma unroll
    for (int mi = 0; mi < 4; ++mi) {
      const int m = m0 + wr*64 + mi*16 + l15;
      floatx4 d = acc[mi][nj];
      float4 s4 = make_float4(d[0]+b4.x, d[1]+b4.y, d[2]+b4.z, d[3]+b4.w);
      *(float4*)(outp + (size_t)m*D_MODEL + nb) = s4;
    }
  }
}

// ---------------------------------------------------------------------------
// MFMA flash attention. Grid (64 bh, 16 pid), 256 thr = 4 waves, 16 q/wave.
// XCD locality: flat = bh + 64*pid -> XCD = bh%8; each bh's 16 blocks
// colocate, K/V (512 KB/bh) stay L2-resident.  [r8-measured: 118 us,
// FETCH 37 MB, Occupancy 40%, MfmaUtil 18 — do not touch]
// Balanced pairing: block pid handles query-blocks {31-pid, pid} -> every
// block runs exactly 33 K-tile iterations (uniform makespan).
//  phase 1: S^T = K·Q^T (16x16x32 f16); C: col=query=lane&15, row=key.
//  softmax: per-query stats; l kept per-lane-partial, reduced in epilogue.
//  phase 2: O^T = V^T·P^T (16x16x16 f16); P^T B-frag == S^T C-layout.
// Wave-uniform ktmax skips fully-masked 16-key subtiles on the diagonal.
// ---------------------------------------------------------------------------
__global__ __launch_bounds__(256, 6)
void attn_fwd(const _Float16* __restrict__ Q, const _Float16* __restrict__ K,
              const _Float16* __restrict__ Vt, u16* __restrict__ O)
{
  __shared__ __align__(16) _Float16 Ks[64][72];
  __shared__ __align__(16) _Float16 Vs[64][72];

  const int bh   = blockIdx.x;              // 0..63  (bh%8 = home XCD)
  const int pid  = blockIdx.y;              // 0..15
  const int t    = threadIdx.x;
  const int w    = t >> 6, lane = t & 63;
  const int quad = lane >> 4, l15 = lane & 15;
  const int sr = t >> 3, sc8 = (t & 7) * 8;
  const _Float16* Kb = K  + (size_t)bh * SEQ * DK;
  const _Float16* Vb = Vt + (size_t)bh * DK * SEQ;

#pragma unroll 1
  for (int item = 0; item < 2; ++item) {
    const int rblk = item ? pid : (SEQ/64 - 1 - pid);   // heavy half first
    const int r0   = rblk * 64;
    const int qb   = r0 + w * 16;
    const int query = qb + l15;

    half8_t qf[2];
    {
      const _Float16* Qp = Q + ((size_t)bh * SEQ + query) * DK + quad * 8;
      qf[0] = *(const half8_t*)(Qp);
      qf[1] = *(const half8_t*)(Qp + 32);
    }

    float mrow = -1e30f, lpart = 0.f;
    floatx4 o[4] = {};

    const int jend = r0 + 64;
    for (int j0 = 0; j0 < jend; j0 += 64) {
      __syncthreads();
      *(uint4*)&Ks[sr     ][sc8] = *(const uint4*)(Kb + (size_t)(j0 + sr     )*DK + sc8);
      *(uint4*)&Ks[sr + 32][sc8] = *(const uint4*)(Kb + (size_t)(j0 + sr + 32)*DK + sc8);
      *(uint4*)&Vs[sr     ][sc8] = *(const uint4*)(Vb + (size_t)(sr     )*SEQ + j0 + sc8);
      *(uint4*)&Vs[sr + 32][sc8] = *(const uint4*)(Vb + (size_t)(sr + 32)*SEQ + j0 + sc8);
      __syncthreads();
      if (j0 > qb + 15) continue;                      // fully masked for wave
      const int ktmax = ((qb + 15 - j0) >> 4) + 1;     // 1..4, wave-uniform

      // ---- phase 1
      floatx4 st[4];
#pragma unroll
      for (int kt = 0; kt < 4; ++kt) {
        if (kt < ktmax) {
          half8_t a0 = *(const half8_t*)&Ks[kt*16 + l15][quad*8];
          half8_t a1 = *(const half8_t*)&Ks[kt*16 + l15][32 + quad*8];
          floatx4 s = {};
          s = __builtin_amdgcn_mfma_f32_16x16x32_f16(a0, qf[0], s, 0, 0, 0);
          s = __builtin_amdgcn_mfma_f32_16x16x32_f16(a1, qf[1], s, 0, 0, 0);
          st[kt] = s;
        }
      }
      // ---- causal mask (only subtiles straddling the diagonal)
#pragma unroll
      for (int kt = 0; kt < 4; ++kt) {
        if (kt < ktmax && j0 + kt*16 + 15 > qb) {
#pragma unroll
          for (int r = 0; r < 4; ++r)
            if (j0 + kt*16 + quad*4 + r > query) st[kt][r] = -1e30f;
        }
      }
      // ---- online softmax (log2 domain; Q pre-scaled by 0.125*log2e)
      float m0 = -1e30f;
#pragma unroll
      for (int kt = 0; kt < 4; ++kt)
        if (kt < ktmax)
          m0 = fmaxf(m0, fmaxf(fmaxf(st[kt][0], st[kt][1]), fmaxf(st[kt][2], st[kt][3])));
      m0 = fmaxf(m0, __shfl_xor(m0, 16));
      m0 = fmaxf(m0, __shfl_xor(m0, 32));
      const float mn    = fmaxf(mrow, m0);
      const float alpha = exp2f(mrow - mn);            // 0 on first live tile
      mrow = mn;
      lpart *= alpha;
      half4_t pf[4];
#pragma unroll
      for (int kt = 0; kt < 4; ++kt) {
        if (kt < ktmax) {
          const float p0 = exp2f(st[kt][0] - mn), p1 = exp2f(st[kt][1] - mn);
          const float p2 = exp2f(st[kt][2] - mn), p3 = exp2f(st[kt][3] - mn);
          lpart += (p0 + p1) + (p2 + p3);
          union { half4_t h; uint2 u; } pc;
          pc.u = make_uint2(pkh(p0, p1), pkh(p2, p3));
          pf[kt] = pc.h;
        }
      }
#pragma unroll
      for (int dt = 0; dt < 4; ++dt) {
        o[dt][0] *= alpha; o[dt][1] *= alpha; o[dt][2] *= alpha; o[dt][3] *= alpha;
      }
      // ---- phase 2
#pragma unroll
      for (int dt = 0; dt < 4; ++dt)
#pragma unroll
        for (int kt = 0; kt < 4; ++kt) {
          if (kt < ktmax) {
            half4_t vf = *(const half4_t*)&Vs[dt*16 + l15][kt*16 + quad*4];
            o[dt] = __builtin_amdgcn_mfma_f32_16x16x16f16(vf, pf[kt], o[dt], 0, 0, 0);
          }
        }
    }

    // ---- epilogue: deferred l reduction, O bf16 [B,S,D]
    float l = lpart;
    l += __shfl_xor(l, 16);
    l += __shfl_xor(l, 32);
    const float inv = 1.0f / l;
    const int b = bh >> 4, h = bh & 15;
    u16* Op = O + ((size_t)(b * SEQ + query)) * D_MODEL + h * DK + quad * 4;
#pragma unroll
    for (int dt = 0; dt < 4; ++dt) {
      u32 lo = ((u32)f2bf(o[dt][1] * inv) << 16) | f2bf(o[dt][0] * inv);
      u32 hi = ((u32)f2bf(o[dt][3] * inv) << 16) | f2bf(o[dt][2] * inv);
      *(uint2*)(Op + dt * 16) = make_uint2(lo, hi);
    }
  }
}

// ---------------------------------------------------------------------------
extern "C" void kernel_launch(void* const* d_in, const int* in_sizes, int n_in,
                              void* d_out, int out_size, void* d_ws, size_t ws_size,
                              hipStream_t stream)
{
  const float* x  = (const float*)d_in[0];
  const float* Wq = (const float*)d_in[1];
  const float* bq = (const float*)d_in[2];
  const float* Wk = (const float*)d_in[3];
  const float* bk = (const float*)d_in[4];
  const float* Wv = (const float*)d_in[5];
  const float* bv = (const float*)d_in[6];
  const float* Wo = (const float*)d_in[7];
  const float* bo = (const float*)d_in[8];

  const size_t tsz = (size_t)MTOT * D_MODEL;
  u16* Qw  = (u16*)d_ws;
  u16* Kw  = Qw + tsz;
  u16* Vtw = Kw + tsz;
  u16* S3  = Vtw + tsz;      // shared slot: xb (pre-attn) then O (post-attn)

  // x -> bf16 (trunc, same rounding as the in-GEMM pk8 path)
  to_bf16<<<(MTOT*D_MODEL)/(256*8), 256, 0, stream>>>(x, S3);

  // fused QKV: which on slow grid axis; 1536 blocks = 24 waves/CU
  gemm_qkv<<<dim3(MTOT/128, 24), 256, 0, stream>>>(
      S3, Wq, bq, Wk, bk, Wv, bv, Qw, Kw, Vtw);

  attn_fwd<<<dim3(BATCH*NHEAD, SEQ/128), 256, 0, stream>>>(
      (const _Float16*)Qw, (const _Float16*)Kw, (const _Float16*)Vtw, S3);

  gemm_out<<<dim3(MTOT/128, D_MODEL/64), 128, 0, stream>>>(
      S3, Wo, bo, (float*)d_out);
}

// Round 21
// 322.621 us; speedup vs baseline: 1.4319x; 1.4319x over previous
//
#include <hip/hip_runtime.h>
#include <stdint.h>

// CausalMultiHeadAttention — round 13 (resubmit; prior bench was an infra
// GPUAcquisitionTimeout, no counters produced).
// r19 post-mortem: merged QKV refuted twice (255 us vs 171 separate) —
// dropped. WRITE_SIZE decoded: it counts the global_load_lds delivery leg
// (2x16B x thr x iters x blocks matches 300-400MB exactly); the r6/r7
// "write amplification" was an artifact. Occupancy ~30% cap = acc AGPRs
// (+64) on the unified file -> ~3 waves/SIMD; wave-pool levers closed.
// This round (on the r12-measured 356.6 us base, ONE lever): W pre-convert
// to bf16 — the last untested falsification branch. Removes ALL in-loop
// VALU staging (B-side pk8 -> gload16) and halves W fetch. ws placement:
//  - Wq/Wk/Wv bf16 (6 MB) -> d_out used as scratch (dead until gemm_out).
//  - Wo bf16 (2 MB) -> Qw slot, converted AFTER attn (Qw dead post-attn).
// attn (r8-measured 118 us) byte-identical. gemm structure = r12 (128x64,
// 128 thr, single-buffer) with B-staging switched to gload16.
// ws: Q | K | Vt (fp16) | {xb then O} (bf16) = 67.1 MB (proven size).

#define D_MODEL 1024
#define NHEAD   16
#define DK      64
#define BATCH   4
#define SEQ     2048
#define MTOT    (BATCH*SEQ)   // 8192

typedef unsigned short u16;
typedef unsigned int   u32;
typedef __bf16    bf16x8  __attribute__((ext_vector_type(8)));
typedef float     floatx4 __attribute__((ext_vector_type(4)));
typedef __fp16    fp16x2  __attribute__((ext_vector_type(2)));
typedef _Float16  half4_t __attribute__((ext_vector_type(4)));
typedef _Float16  half8_t __attribute__((ext_vector_type(8)));

// round-to-nearest-even f32 -> bf16 (epilogue only)
__device__ __forceinline__ u16 f2bf(float f){
  union { float f; u32 u; } c; c.f = f;
  u32 x = c.u;
  x += 0x7fffu + ((x >> 16) & 1u);
  return (u16)(x >> 16);
}
// f32 pair -> packed fp16 bits (RTZ, hardware packed cvt)
__device__ __forceinline__ u32 pkh(float a, float b){
  union { fp16x2 h; u32 u; } c; c.h = __builtin_amdgcn_cvt_pkrtz(a, b); return c.u;
}
// 8 fp32 -> 8 bf16 by truncation: one v_perm per pair
__device__ __forceinline__ uint4 pk8(const float* __restrict__ p){
  uint4 a = *(const uint4*)p;
  uint4 b = *(const uint4*)(p + 4);
  uint4 r;
  r.x = __builtin_amdgcn_perm(a.y, a.x, 0x07060302);
  r.y = __builtin_amdgcn_perm(a.w, a.z, 0x07060302);
  r.z = __builtin_amdgcn_perm(b.y, b.x, 0x07060302);
  r.w = __builtin_amdgcn_perm(b.w, b.z, 0x07060302);
  return r;
}
// async global->LDS, 16B per lane. LDS dest must be linear in lane order.
__device__ __forceinline__ void gload16(const void* g, void* l){
  __builtin_amdgcn_global_load_lds(
      (const __attribute__((address_space(1))) u32*)g,
      (__attribute__((address_space(3))) u32*)l, 16, 0, 0);
}

// ---------------------------------------------------------------------------
// Combined pre-pass: x (4096 blocks) + Wq/Wk/Wv (512 blocks each) -> bf16.
// Block ranges select the stream; all use the pk8 truncation path.
// ---------------------------------------------------------------------------
__global__ __launch_bounds__(256)
void conv4(const float* __restrict__ x,  u16* __restrict__ xb,
           const float* __restrict__ wq, const float* __restrict__ wk,
           const float* __restrict__ wv, u16* __restrict__ wb)
{
  const int b = blockIdx.x;
  const float* s; u16* d; size_t base;
  if (b < 4096)      { s = x;  d = xb;            base = (size_t)b * 2048; }
  else if (b < 4608) { s = wq; d = wb;            base = (size_t)(b-4096) * 2048; }
  else if (b < 5120) { s = wk; d = wb + (1u<<20); base = (size_t)(b-4608) * 2048; }
  else               { s = wv; d = wb + (2u<<20); base = (size_t)(b-5120) * 2048; }
  const size_t i = base + (size_t)threadIdx.x * 8;
  *(uint4*)(d + i) = pk8(s + i);
}

// single-matrix fp32 -> bf16 (Wo, post-attn, into the dead Qw slot)
__global__ __launch_bounds__(256)
void conv1(const float* __restrict__ s, u16* __restrict__ d)
{
  const size_t i = ((size_t)blockIdx.x * 256 + threadIdx.x) * 8;
  *(uint4*)(d + i) = pk8(s + i);
}

// ---------------------------------------------------------------------------
// GEMM: C[m,n] = (sum_k A[m,k]*W[n,k] + bias[n]) * scale.  A: MxK bf16,
// W: NxK bf16 (both pre-converted) — BOTH staged via global_load_lds:
// zero VALU staging in the K-loop.
// 128x64 tile, BK=32, 128 thr = 2 waves stacked in m; each wave owns 64x64.
// Grid (64 m-tiles, 16 n-tiles) = 1024 blocks (r12-measured structure).
//   MODE 0 (fp32 [m][N], d_out) / MODE 1 (fp16 [bh][s][dk]): mfma(W,A) ->
//     lane=m, regs=n-consecutive -> float4 / uint2 stores.
//   MODE 2 (fp16 [bh][dk][s], V^T): mfma(A,W) -> lane=n(dd), regs=m(s)
//     -> uint2 stores contiguous in s.
// ---------------------------------------------------------------------------
template<int MODE>
__global__ __launch_bounds__(128, 2)
void gemm_bt(const u16* __restrict__ A, const u16* __restrict__ W,
             const float* __restrict__ bias, void* __restrict__ outv,
             float scale)
{
  __shared__ __align__(16) u16 As[128*32];   // 8 KB
  __shared__ __align__(16) u16 Bs[64*32];    // 4 KB

  const int t    = threadIdx.x;              // 0..127
  const int m0   = blockIdx.x * 128;
  const int n0   = blockIdx.y * 64;
  const int wid  = t >> 6, lane = t & 63;
  const int wr   = wid;                      // wave row 0..1
  const int quad = lane >> 4, l15 = lane & 15;

  // staging: chunk c -> row = c>>2, koff = (c&3)*8 ; LDS [row][32 u16].
  const int rS = t >> 2;                     // 0..31
  const int kS = (t & 3) * 8;

  const u16* Ap = A + (size_t)(m0 + rS)*D_MODEL + kS;
  const u16* Wp = W + (size_t)(n0 + rS)*D_MODEL + kS;

  floatx4 acc[4][4] = {};

  for (int k0 = 0; k0 < D_MODEL; k0 += 32) {
    __syncthreads();
    gload16(Ap + k0,               (char*)As + t*16);
    gload16(Ap + k0 + 32*D_MODEL,  (char*)As + 2048 + t*16);
    gload16(Ap + k0 + 64*D_MODEL,  (char*)As + 4096 + t*16);
    gload16(Ap + k0 + 96*D_MODEL,  (char*)As + 6144 + t*16);
    gload16(Wp + k0,               (char*)Bs + t*16);
    gload16(Wp + k0 + 32*D_MODEL,  (char*)Bs + 2048 + t*16);
    __syncthreads();   // compiler emits vmcnt(0)+lgkmcnt(0) drain here

    bf16x8 af[4], bf[4];
#pragma unroll
    for (int i = 0; i < 4; ++i) {
      af[i] = *(const bf16x8*)&As[(wr*64 + i*16 + l15)*32 + quad*8];
      bf[i] = *(const bf16x8*)&Bs[(i*16 + l15)*32 + quad*8];
    }
#pragma unroll
    for (int mi = 0; mi < 4; ++mi)
#pragma unroll
      for (int nj = 0; nj < 4; ++nj) {
        if (MODE == 2)
          acc[mi][nj] = __builtin_amdgcn_mfma_f32_16x16x32_bf16(af[mi], bf[nj], acc[mi][nj], 0, 0, 0);
        else
          acc[mi][nj] = __builtin_amdgcn_mfma_f32_16x16x32_bf16(bf[nj], af[mi], acc[mi][nj], 0, 0, 0);
      }
  }

  if (MODE != 2) {
    // lane = m, regs = n-consecutive
#pragma unroll
    for (int nj = 0; nj < 4; ++nj) {
      const int nb = n0 + nj*16 + quad*4;
      const float4 b4 = *(const float4*)(bias + nb);
#pragma unroll
      for (int mi = 0; mi < 4; ++mi) {
        const int m = m0 + wr*64 + mi*16 + l15;
        floatx4 d = acc[mi][nj];
        const float v0 = (d[0]+b4.x)*scale, v1 = (d[1]+b4.y)*scale;
        const float v2 = (d[2]+b4.z)*scale, v3 = (d[3]+b4.w)*scale;
        if (MODE == 0) {
          float4 s4 = make_float4(v0, v1, v2, v3);
          *(float4*)((float*)outv + (size_t)m*D_MODEL + nb) = s4;
        } else {
          const int b = m >> 11, s = m & 2047, h = nb >> 6, dd = nb & 63;
          u16* dst = (u16*)outv + ((((size_t)b*NHEAD + h)*SEQ + s) << 6) + dd;
          *(uint2*)dst = make_uint2(pkh(v0, v1), pkh(v2, v3));
        }
      }
    }
  } else {
    // lane = n (dd), regs = m (s)-consecutive
#pragma unroll
    for (int nj = 0; nj < 4; ++nj) {
      const int n  = n0 + nj*16 + l15;
      const float bvv = bias[n];
      const int h = n >> 6, dd = n & 63;
#pragma unroll
      for (int mi = 0; mi < 4; ++mi) {
        const int mb = m0 + wr*64 + mi*16 + quad*4;
        const int b = mb >> 11, s = mb & 2047;
        floatx4 d = acc[mi][nj];
        u16* dst = (u16*)outv + (((size_t)b*NHEAD + h)*DK + dd)*SEQ + s;
        *(uint2*)dst = make_uint2(pkh(d[0]+bvv, d[1]+bvv), pkh(d[2]+bvv, d[3]+bvv));
      }
    }
  }
}

// ---------------------------------------------------------------------------
// MFMA flash attention. Grid (64 bh, 16 pid), 256 thr = 4 waves, 16 q/wave.
// XCD locality: flat = bh + 64*pid -> XCD = bh%8; each bh's 16 blocks
// colocate, K/V (512 KB/bh) stay L2-resident.  [r8-measured: 118 us,
// FETCH 37 MB, Occupancy 40%, MfmaUtil 18 — do not touch]
// Balanced pairing: block pid handles query-blocks {31-pid, pid} -> every
// block runs exactly 33 K-tile iterations (uniform makespan).
//  phase 1: S^T = K·Q^T (16x16x32 f16); C: col=query=lane&15, row=key.
//  softmax: per-query stats; l kept per-lane-partial, reduced in epilogue.
//  phase 2: O^T = V^T·P^T (16x16x16 f16); P^T B-frag == S^T C-layout.
// Wave-uniform ktmax skips fully-masked 16-key subtiles on the diagonal.
// ---------------------------------------------------------------------------
__global__ __launch_bounds__(256, 6)
void attn_fwd(const _Float16* __restrict__ Q, const _Float16* __restrict__ K,
              const _Float16* __restrict__ Vt, u16* __restrict__ O)
{
  __shared__ __align__(16) _Float16 Ks[64][72];
  __shared__ __align__(16) _Float16 Vs[64][72];

  const int bh   = blockIdx.x;              // 0..63  (bh%8 = home XCD)
  const int pid  = blockIdx.y;              // 0..15
  const int t    = threadIdx.x;
  const int w    = t >> 6, lane = t & 63;
  const int quad = lane >> 4, l15 = lane & 15;
  const int sr = t >> 3, sc8 = (t & 7) * 8;
  const _Float16* Kb = K  + (size_t)bh * SEQ * DK;
  const _Float16* Vb = Vt + (size_t)bh * DK * SEQ;

#pragma unroll 1
  for (int item = 0; item < 2; ++item) {
    const int rblk = item ? pid : (SEQ/64 - 1 - pid);   // heavy half first
    const int r0   = rblk * 64;
    const int qb   = r0 + w * 16;
    const int query = qb + l15;

    half8_t qf[2];
    {
      const _Float16* Qp = Q + ((size_t)bh * SEQ + query) * DK + quad * 8;
      qf[0] = *(const half8_t*)(Qp);
      qf[1] = *(const half8_t*)(Qp + 32);
    }

    float mrow = -1e30f, lpart = 0.f;
    floatx4 o[4] = {};

    const int jend = r0 + 64;
    for (int j0 = 0; j0 < jend; j0 += 64) {
      __syncthreads();
      *(uint4*)&Ks[sr     ][sc8] = *(const uint4*)(Kb + (size_t)(j0 + sr     )*DK + sc8);
      *(uint4*)&Ks[sr + 32][sc8] = *(const uint4*)(Kb + (size_t)(j0 + sr + 32)*DK + sc8);
      *(uint4*)&Vs[sr     ][sc8] = *(const uint4*)(Vb + (size_t)(sr     )*SEQ + j0 + sc8);
      *(uint4*)&Vs[sr + 32][sc8] = *(const uint4*)(Vb + (size_t)(sr + 32)*SEQ + j0 + sc8);
      __syncthreads();
      if (j0 > qb + 15) continue;                      // fully masked for wave
      const int ktmax = ((qb + 15 - j0) >> 4) + 1;     // 1..4, wave-uniform

      // ---- phase 1
      floatx4 st[4];
#pragma unroll
      for (int kt = 0; kt < 4; ++kt) {
        if (kt < ktmax) {
          half8_t a0 = *(const half8_t*)&Ks[kt*16 + l15][quad*8];
          half8_t a1 = *(const half8_t*)&Ks[kt*16 + l15][32 + quad*8];
          floatx4 s = {};
          s = __builtin_amdgcn_mfma_f32_16x16x32_f16(a0, qf[0], s, 0, 0, 0);
          s = __builtin_amdgcn_mfma_f32_16x16x32_f16(a1, qf[1], s, 0, 0, 0);
          st[kt] = s;
        }
      }
      // ---- causal mask (only subtiles straddling the diagonal)
#pragma unroll
      for (int kt = 0; kt < 4; ++kt) {
        if (kt < ktmax && j0 + kt*16 + 15 > qb) {
#pragma unroll
          for (int r = 0; r < 4; ++r)
            if (j0 + kt*16 + quad*4 + r > query) st[kt][r] = -1e30f;
        }
      }
      // ---- online softmax (log2 domain; Q pre-scaled by 0.125*log2e)
      float m0 = -1e30f;
#pragma unroll
      for (int kt = 0; kt < 4; ++kt)
        if (kt < ktmax)
          m0 = fmaxf(m0, fmaxf(fmaxf(st[kt][0], st[kt][1]), fmaxf(st[kt][2], st[kt][3])));
      m0 = fmaxf(m0, __shfl_xor(m0, 16));
      m0 = fmaxf(m0, __shfl_xor(m0, 32));
      const float mn    = fmaxf(mrow, m0);
      const float alpha = exp2f(mrow - mn);            // 0 on first live tile
      mrow = mn;
      lpart *= alpha;
      half4_t pf[4];
#pragma unroll
      for (int kt = 0; kt < 4; ++kt) {
        if (kt < ktmax) {
          const float p0 = exp2f(st[kt][0] - mn), p1 = exp2f(st[kt][1] - mn);
          const float p2 = exp2f(st[kt][2] - mn), p3 = exp2f(st[kt][3] - mn);
          lpart += (p0 + p1) + (p2 + p3);
          union { half4_t h; uint2 u; } pc;
          pc.u = make_uint2(pkh(p0, p1), pkh(p2, p3));
          pf[kt] = pc.h;
        }
      }
#pragma unroll
      for (int dt = 0; dt < 4; ++dt) {
        o[dt][0] *= alpha; o[dt][1] *= alpha; o[dt][2] *= alpha; o[dt][3] *= alpha;
      }
      // ---- phase 2
#pragma unroll
      for (int dt = 0; dt < 4; ++dt)
#pragma unroll
        for (int kt = 0; kt < 4; ++kt) {
          if (kt < ktmax) {
            half4_t vf = *(const half4_t*)&Vs[dt*16 + l15][kt*16 + quad*4];
            o[dt] = __builtin_amdgcn_mfma_f32_16x16x16f16(vf, pf[kt], o[dt], 0, 0, 0);
          }
        }
    }

    // ---- epilogue: deferred l reduction, O bf16 [B,S,D]
    float l = lpart;
    l += __shfl_xor(l, 16);
    l += __shfl_xor(l, 32);
    const float inv = 1.0f / l;
    const int b = bh >> 4, h = bh & 15;
    u16* Op = O + ((size_t)(b * SEQ + query)) * D_MODEL + h * DK + quad * 4;
#pragma unroll
    for (int dt = 0; dt < 4; ++dt) {
      u32 lo = ((u32)f2bf(o[dt][1] * inv) << 16) | f2bf(o[dt][0] * inv);
      u32 hi = ((u32)f2bf(o[dt][3] * inv) << 16) | f2bf(o[dt][2] * inv);
      *(uint2*)(Op + dt * 16) = make_uint2(lo, hi);
    }
  }
}

// ---------------------------------------------------------------------------
extern "C" void kernel_launch(void* const* d_in, const int* in_sizes, int n_in,
                              void* d_out, int out_size, void* d_ws, size_t ws_size,
                              hipStream_t stream)
{
  const float* x  = (const float*)d_in[0];
  const float* Wq = (const float*)d_in[1];
  const float* bq = (const float*)d_in[2];
  const float* Wk = (const float*)d_in[3];
  const float* bk = (const float*)d_in[4];
  const float* Wv = (const float*)d_in[5];
  const float* bv = (const float*)d_in[6];
  const float* Wo = (const float*)d_in[7];
  const float* bo = (const float*)d_in[8];

  const size_t tsz = (size_t)MTOT * D_MODEL;
  u16* Qw  = (u16*)d_ws;
  u16* Kw  = Qw + tsz;
  u16* Vtw = Kw + tsz;
  u16* S3  = Vtw + tsz;      // shared slot: xb (pre-attn) then O (post-attn)
  u16* WB  = (u16*)d_out;    // d_out as scratch: Wq|Wk|Wv bf16 (6 MB),
                             // dead until gemm_out overwrites it at the end.

  // x -> S3, Wq/Wk/Wv -> d_out scratch (all pk8 truncation)
  conv4<<<4096 + 3*512, 256, 0, stream>>>(x, S3, Wq, Wk, Wv, WB);

  dim3 gg(MTOT/128, D_MODEL/64);               // (64 m-tiles, 16 n-tiles)
  // Q scale = 1/sqrt(dk) * log2(e): softmax runs in log2 domain
  gemm_bt<1><<<gg, 128, 0, stream>>>(S3, WB,            bq, Qw,  0.18033688f);
  gemm_bt<1><<<gg, 128, 0, stream>>>(S3, WB + (1u<<20), bk, Kw,  1.0f);
  gemm_bt<2><<<gg, 128, 0, stream>>>(S3, WB + (2u<<20), bv, Vtw, 1.0f);

  attn_fwd<<<dim3(BATCH*NHEAD, SEQ/128), 256, 0, stream>>>(
      (const _Float16*)Qw, (const _Float16*)Kw, (const _Float16*)Vtw, S3);

  // Wo -> bf16 into the now-dead Qw slot, then output projection
  conv1<<<512, 256, 0, stream>>>(Wo, Qw);
  gemm_bt<0><<<gg, 128, 0, stream>>>(S3, Qw, bo, d_out, 1.0f);
}

// Round 22
// 315.125 us; speedup vs baseline: 1.4659x; 1.0238x over previous
//
#include <hip/hip_runtime.h>
#include <stdint.h>

// CausalMultiHeadAttention — round 14.
// r21 post-mortem: W pre-convert CONFIRMED (356.6 -> 322.6; ~48 us/GEMM as
// predicted). GEMM levers exhausted short of full 8-phase rewrite.
// This round (ONE lever): attn item-fusion. The two balanced-pair items
// {31-pid, pid} share K/V tiles (item1's range is a SUBSET of item0's);
// fusing them into one K-tile loop stages each tile ONCE (33 -> 32-pid
// rounds/block, -21-30% per CU), doubling MFMA per barrier on shared tiles.
// Per-item tile order unchanged -> bit-identical accumulation.
// VGPR ~doubles -> launch_bounds(256,4) (16 waves/CU, same as grid cap).
// GEMMs (all-gload16, bf16 W), conv4/conv1: r21-measured, byte-identical.
// ws: Q | K | Vt (fp16) | {xb then O} (bf16) = 67.1 MB (proven size).

#define D_MODEL 1024
#define NHEAD   16
#define DK      64
#define BATCH   4
#define SEQ     2048
#define MTOT    (BATCH*SEQ)   // 8192

typedef unsigned short u16;
typedef unsigned int   u32;
typedef __bf16    bf16x8  __attribute__((ext_vector_type(8)));
typedef float     floatx4 __attribute__((ext_vector_type(4)));
typedef __fp16    fp16x2  __attribute__((ext_vector_type(2)));
typedef _Float16  half4_t __attribute__((ext_vector_type(4)));
typedef _Float16  half8_t __attribute__((ext_vector_type(8)));

// round-to-nearest-even f32 -> bf16 (epilogue only)
__device__ __forceinline__ u16 f2bf(float f){
  union { float f; u32 u; } c; c.f = f;
  u32 x = c.u;
  x += 0x7fffu + ((x >> 16) & 1u);
  return (u16)(x >> 16);
}
// f32 pair -> packed fp16 bits (RTZ, hardware packed cvt)
__device__ __forceinline__ u32 pkh(float a, float b){
  union { fp16x2 h; u32 u; } c; c.h = __builtin_amdgcn_cvt_pkrtz(a, b); return c.u;
}
// 8 fp32 -> 8 bf16 by truncation: one v_perm per pair
__device__ __forceinline__ uint4 pk8(const float* __restrict__ p){
  uint4 a = *(const uint4*)p;
  uint4 b = *(const uint4*)(p + 4);
  uint4 r;
  r.x = __builtin_amdgcn_perm(a.y, a.x, 0x07060302);
  r.y = __builtin_amdgcn_perm(a.w, a.z, 0x07060302);
  r.z = __builtin_amdgcn_perm(b.y, b.x, 0x07060302);
  r.w = __builtin_amdgcn_perm(b.w, b.z, 0x07060302);
  return r;
}
// async global->LDS, 16B per lane. LDS dest must be linear in lane order.
__device__ __forceinline__ void gload16(const void* g, void* l){
  __builtin_amdgcn_global_load_lds(
      (const __attribute__((address_space(1))) u32*)g,
      (__attribute__((address_space(3))) u32*)l, 16, 0, 0);
}

// ---------------------------------------------------------------------------
// Combined pre-pass: x (4096 blocks) + Wq/Wk/Wv (512 blocks each) -> bf16.
// ---------------------------------------------------------------------------
__global__ __launch_bounds__(256)
void conv4(const float* __restrict__ x,  u16* __restrict__ xb,
           const float* __restrict__ wq, const float* __restrict__ wk,
           const float* __restrict__ wv, u16* __restrict__ wb)
{
  const int b = blockIdx.x;
  const float* s; u16* d; size_t base;
  if (b < 4096)      { s = x;  d = xb;            base = (size_t)b * 2048; }
  else if (b < 4608) { s = wq; d = wb;            base = (size_t)(b-4096) * 2048; }
  else if (b < 5120) { s = wk; d = wb + (1u<<20); base = (size_t)(b-4608) * 2048; }
  else               { s = wv; d = wb + (2u<<20); base = (size_t)(b-5120) * 2048; }
  const size_t i = base + (size_t)threadIdx.x * 8;
  *(uint4*)(d + i) = pk8(s + i);
}

// single-matrix fp32 -> bf16 (Wo, post-attn, into the dead Qw slot)
__global__ __launch_bounds__(256)
void conv1(const float* __restrict__ s, u16* __restrict__ d)
{
  const size_t i = ((size_t)blockIdx.x * 256 + threadIdx.x) * 8;
  *(uint4*)(d + i) = pk8(s + i);
}

// ---------------------------------------------------------------------------
// GEMM (r21-measured, ~48 us): A MxK bf16, W NxK bf16, BOTH via gload16.
// 128x64 tile, BK=32, 128 thr = 2 waves stacked in m; each wave owns 64x64.
// Grid (64 m-tiles, 16 n-tiles) = 1024 blocks.
// ---------------------------------------------------------------------------
template<int MODE>
__global__ __launch_bounds__(128, 2)
void gemm_bt(const u16* __restrict__ A, const u16* __restrict__ W,
             const float* __restrict__ bias, void* __restrict__ outv,
             float scale)
{
  __shared__ __align__(16) u16 As[128*32];   // 8 KB
  __shared__ __align__(16) u16 Bs[64*32];    // 4 KB

  const int t    = threadIdx.x;              // 0..127
  const int m0   = blockIdx.x * 128;
  const int n0   = blockIdx.y * 64;
  const int wid  = t >> 6, lane = t & 63;
  const int wr   = wid;                      // wave row 0..1
  const int quad = lane >> 4, l15 = lane & 15;

  const int rS = t >> 2;                     // 0..31
  const int kS = (t & 3) * 8;

  const u16* Ap = A + (size_t)(m0 + rS)*D_MODEL + kS;
  const u16* Wp = W + (size_t)(n0 + rS)*D_MODEL + kS;

  floatx4 acc[4][4] = {};

  for (int k0 = 0; k0 < D_MODEL; k0 += 32) {
    __syncthreads();
    gload16(Ap + k0,               (char*)As + t*16);
    gload16(Ap + k0 + 32*D_MODEL,  (char*)As + 2048 + t*16);
    gload16(Ap + k0 + 64*D_MODEL,  (char*)As + 4096 + t*16);
    gload16(Ap + k0 + 96*D_MODEL,  (char*)As + 6144 + t*16);
    gload16(Wp + k0,               (char*)Bs + t*16);
    gload16(Wp + k0 + 32*D_MODEL,  (char*)Bs + 2048 + t*16);
    __syncthreads();

    bf16x8 af[4], bf[4];
#pragma unroll
    for (int i = 0; i < 4; ++i) {
      af[i] = *(const bf16x8*)&As[(wr*64 + i*16 + l15)*32 + quad*8];
      bf[i] = *(const bf16x8*)&Bs[(i*16 + l15)*32 + quad*8];
    }
#pragma unroll
    for (int mi = 0; mi < 4; ++mi)
#pragma unroll
      for (int nj = 0; nj < 4; ++nj) {
        if (MODE == 2)
          acc[mi][nj] = __builtin_amdgcn_mfma_f32_16x16x32_bf16(af[mi], bf[nj], acc[mi][nj], 0, 0, 0);
        else
          acc[mi][nj] = __builtin_amdgcn_mfma_f32_16x16x32_bf16(bf[nj], af[mi], acc[mi][nj], 0, 0, 0);
      }
  }

  if (MODE != 2) {
#pragma unroll
    for (int nj = 0; nj < 4; ++nj) {
      const int nb = n0 + nj*16 + quad*4;
      const float4 b4 = *(const float4*)(bias + nb);
#pragma unroll
      for (int mi = 0; mi < 4; ++mi) {
        const int m = m0 + wr*64 + mi*16 + l15;
        floatx4 d = acc[mi][nj];
        const float v0 = (d[0]+b4.x)*scale, v1 = (d[1]+b4.y)*scale;
        const float v2 = (d[2]+b4.z)*scale, v3 = (d[3]+b4.w)*scale;
        if (MODE == 0) {
          float4 s4 = make_float4(v0, v1, v2, v3);
          *(float4*)((float*)outv + (size_t)m*D_MODEL + nb) = s4;
        } else {
          const int b = m >> 11, s = m & 2047, h = nb >> 6, dd = nb & 63;
          u16* dst = (u16*)outv + ((((size_t)b*NHEAD + h)*SEQ + s) << 6) + dd;
          *(uint2*)dst = make_uint2(pkh(v0, v1), pkh(v2, v3));
        }
      }
    }
  } else {
#pragma unroll
    for (int nj = 0; nj < 4; ++nj) {
      const int n  = n0 + nj*16 + l15;
      const float bvv = bias[n];
      const int h = n >> 6, dd = n & 63;
#pragma unroll
      for (int mi = 0; mi < 4; ++mi) {
        const int mb = m0 + wr*64 + mi*16 + quad*4;
        const int b = mb >> 11, s = mb & 2047;
        floatx4 d = acc[mi][nj];
        u16* dst = (u16*)outv + (((size_t)b*NHEAD + h)*DK + dd)*SEQ + s;
        *(uint2*)dst = make_uint2(pkh(d[0]+bvv, d[1]+bvv), pkh(d[2]+bvv, d[3]+bvv));
      }
    }
  }
}

// ---------------------------------------------------------------------------
// Per-tile attention compute (one item): phase1 QK^T, mask, online softmax,
// phase2 PV. Identical math/order to the r8-measured kernel.
// ---------------------------------------------------------------------------
__device__ __forceinline__ void attn_tile(
    const _Float16 (*Ks)[72], const _Float16 (*Vs)[72],
    int j0, int qb, int query, int quad, int l15,
    const half8_t* qf, float& mrow, float& lpart, floatx4* o)
{
  const int ktmax = ((qb + 15 - j0) >> 4) + 1;     // 1..4+, wave-uniform

  floatx4 st[4];
#pragma unroll
  for (int kt = 0; kt < 4; ++kt) {
    if (kt < ktmax) {
      half8_t a0 = *(const half8_t*)&Ks[kt*16 + l15][quad*8];
      half8_t a1 = *(const half8_t*)&Ks[kt*16 + l15][32 + quad*8];
      floatx4 s = {};
      s = __builtin_amdgcn_mfma_f32_16x16x32_f16(a0, qf[0], s, 0, 0, 0);
      s = __builtin_amdgcn_mfma_f32_16x16x32_f16(a1, qf[1], s, 0, 0, 0);
      st[kt] = s;
    }
  }
#pragma unroll
  for (int kt = 0; kt < 4; ++kt) {
    if (kt < ktmax && j0 + kt*16 + 15 > qb) {
#pragma unroll
      for (int r = 0; r < 4; ++r)
        if (j0 + kt*16 + quad*4 + r > query) st[kt][r] = -1e30f;
    }
  }
  float m0 = -1e30f;
#pragma unroll
  for (int kt = 0; kt < 4; ++kt)
    if (kt < ktmax)
      m0 = fmaxf(m0, fmaxf(fmaxf(st[kt][0], st[kt][1]), fmaxf(st[kt][2], st[kt][3])));
  m0 = fmaxf(m0, __shfl_xor(m0, 16));
  m0 = fmaxf(m0, __shfl_xor(m0, 32));
  const float mn    = fmaxf(mrow, m0);
  const float alpha = exp2f(mrow - mn);            // 0 on first live tile
  mrow = mn;
  lpart *= alpha;
  half4_t pf[4];
#pragma unroll
  for (int kt = 0; kt < 4; ++kt) {
    if (kt < ktmax) {
      const float p0 = exp2f(st[kt][0] - mn), p1 = exp2f(st[kt][1] - mn);
      const float p2 = exp2f(st[kt][2] - mn), p3 = exp2f(st[kt][3] - mn);
      lpart += (p0 + p1) + (p2 + p3);
      union { half4_t h; uint2 u; } pc;
      pc.u = make_uint2(pkh(p0, p1), pkh(p2, p3));
      pf[kt] = pc.h;
    }
  }
#pragma unroll
  for (int dt = 0; dt < 4; ++dt) {
    o[dt][0] *= alpha; o[dt][1] *= alpha; o[dt][2] *= alpha; o[dt][3] *= alpha;
  }
#pragma unroll
  for (int dt = 0; dt < 4; ++dt)
#pragma unroll
    for (int kt = 0; kt < 4; ++kt) {
      if (kt < ktmax) {
        half4_t vf = *(const half4_t*)&Vs[dt*16 + l15][kt*16 + quad*4];
        o[dt] = __builtin_amdgcn_mfma_f32_16x16x16f16(vf, pf[kt], o[dt], 0, 0, 0);
      }
    }
}

// ---------------------------------------------------------------------------
// MFMA flash attention, ITEM-FUSED. Grid (64 bh, 16 pid), 256 thr = 4 waves.
// Block pid owns query-blocks {31-pid (heavy), pid}; item1's K/V tile range
// [0, pid*64+64) is a subset of item0's [0, (31-pid)*64+64) -> ONE staging
// loop serves both: stage tile once, compute item0 then item1 while live.
// Staging rounds/block: 33 -> 32-pid (CU aggregate -21..30%). Per-item tile
// order unchanged -> numerics identical to the r8-measured kernel.
// XCD locality (bh%8) and per-query deferred-l epilogue unchanged.
// ---------------------------------------------------------------------------
__global__ __launch_bounds__(256, 4)
void attn_fwd(const _Float16* __restrict__ Q, const _Float16* __restrict__ K,
              const _Float16* __restrict__ Vt, u16* __restrict__ O)
{
  __shared__ __align__(16) _Float16 Ks[64][72];
  __shared__ __align__(16) _Float16 Vs[64][72];

  const int bh   = blockIdx.x;              // 0..63  (bh%8 = home XCD)
  const int pid  = blockIdx.y;              // 0..15
  const int t    = threadIdx.x;
  const int w    = t >> 6, lane = t & 63;
  const int quad = lane >> 4, l15 = lane & 15;
  const int sr = t >> 3, sc8 = (t & 7) * 8;
  const _Float16* Kb = K  + (size_t)bh * SEQ * DK;
  const _Float16* Vb = Vt + (size_t)bh * DK * SEQ;

  const int rblk0 = 31 - pid;               // heavy item
  const int rblk1 = pid;                    // light item (subset range)
  const int qb0 = rblk0*64 + w*16, q0 = qb0 + l15;
  const int qb1 = rblk1*64 + w*16, q1 = qb1 + l15;

  half8_t qf0[2], qf1[2];
  {
    const _Float16* Qp0 = Q + ((size_t)bh * SEQ + q0) * DK + quad * 8;
    qf0[0] = *(const half8_t*)(Qp0);
    qf0[1] = *(const half8_t*)(Qp0 + 32);
    const _Float16* Qp1 = Q + ((size_t)bh * SEQ + q1) * DK + quad * 8;
    qf1[0] = *(const half8_t*)(Qp1);
    qf1[1] = *(const half8_t*)(Qp1 + 32);
  }

  float mrow0 = -1e30f, lpart0 = 0.f;
  float mrow1 = -1e30f, lpart1 = 0.f;
  floatx4 o0[4] = {};
  floatx4 o1[4] = {};

  const int jend = rblk0*64 + 64;           // item0's range covers item1's
#pragma unroll 1
  for (int j0 = 0; j0 < jend; j0 += 64) {
    __syncthreads();
    *(uint4*)&Ks[sr     ][sc8] = *(const uint4*)(Kb + (size_t)(j0 + sr     )*DK + sc8);
    *(uint4*)&Ks[sr + 32][sc8] = *(const uint4*)(Kb + (size_t)(j0 + sr + 32)*DK + sc8);
    *(uint4*)&Vs[sr     ][sc8] = *(const uint4*)(Vb + (size_t)(sr     )*SEQ + j0 + sc8);
    *(uint4*)&Vs[sr + 32][sc8] = *(const uint4*)(Vb + (size_t)(sr + 32)*SEQ + j0 + sc8);
    __syncthreads();
    if (j0 <= qb0 + 15)
      attn_tile(Ks, Vs, j0, qb0, q0, quad, l15, qf0, mrow0, lpart0, o0);
    if (j0 <= qb1 + 15)
      attn_tile(Ks, Vs, j0, qb1, q1, quad, l15, qf1, mrow1, lpart1, o1);
  }

  // ---- epilogue: deferred l reduction, O bf16 [B,S,D], both items
  const int b = bh >> 4, h = bh & 15;
  {
    float l = lpart0;
    l += __shfl_xor(l, 16);
    l += __shfl_xor(l, 32);
    const float inv = 1.0f / l;
    u16* Op = O + ((size_t)(b * SEQ + q0)) * D_MODEL + h * DK + quad * 4;
#pragma unroll
    for (int dt = 0; dt < 4; ++dt) {
      u32 lo = ((u32)f2bf(o0[dt][1] * inv) << 16) | f2bf(o0[dt][0] * inv);
      u32 hi = ((u32)f2bf(o0[dt][3] * inv) << 16) | f2bf(o0[dt][2] * inv);
      *(uint2*)(Op + dt * 16) = make_uint2(lo, hi);
    }
  }
  {
    float l = lpart1;
    l += __shfl_xor(l, 16);
    l += __shfl_xor(l, 32);
    const float inv = 1.0f / l;
    u16* Op = O + ((size_t)(b * SEQ + q1)) * D_MODEL + h * DK + quad * 4;
#pragma unroll
    for (int dt = 0; dt < 4; ++dt) {
      u32 lo = ((u32)f2bf(o1[dt][1] * inv) << 16) | f2bf(o1[dt][0] * inv);
      u32 hi = ((u32)f2bf(o1[dt][3] * inv) << 16) | f2bf(o1[dt][2] * inv);
      *(uint2*)(Op + dt * 16) = make_uint2(lo, hi);
    }
  }
}

// ---------------------------------------------------------------------------
extern "C" void kernel_launch(void* const* d_in, const int* in_sizes, int n_in,
                              void* d_out, int out_size, void* d_ws, size_t ws_size,
                              hipStream_t stream)
{
  const float* x  = (const float*)d_in[0];
  const float* Wq = (const float*)d_in[1];
  const float* bq = (const float*)d_in[2];
  const float* Wk = (const float*)d_in[3];
  const float* bk = (const float*)d_in[4];
  const float* Wv = (const float*)d_in[5];
  const float* bv = (const float*)d_in[6];
  const float* Wo = (const float*)d_in[7];
  const float* bo = (const float*)d_in[8];

  const size_t tsz = (size_t)MTOT * D_MODEL;
  u16* Qw  = (u16*)d_ws;
  u16* Kw  = Qw + tsz;
  u16* Vtw = Kw + tsz;
  u16* S3  = Vtw + tsz;      // shared slot: xb (pre-attn) then O (post-attn)
  u16* WB  = (u16*)d_out;    // d_out as scratch: Wq|Wk|Wv bf16 (6 MB),
                             // dead until gemm_out overwrites it at the end.

  // x -> S3, Wq/Wk/Wv -> d_out scratch (all pk8 truncation)
  conv4<<<4096 + 3*512, 256, 0, stream>>>(x, S3, Wq, Wk, Wv, WB);

  dim3 gg(MTOT/128, D_MODEL/64);               // (64 m-tiles, 16 n-tiles)
  // Q scale = 1/sqrt(dk) * log2(e): softmax runs in log2 domain
  gemm_bt<1><<<gg, 128, 0, stream>>>(S3, WB,            bq, Qw,  0.18033688f);
  gemm_bt<1><<<gg, 128, 0, stream>>>(S3, WB + (1u<<20), bk, Kw,  1.0f);
  gemm_bt<2><<<gg, 128, 0, stream>>>(S3, WB + (2u<<20), bv, Vtw, 1.0f);

  attn_fwd<<<dim3(BATCH*NHEAD, SEQ/128), 256, 0, stream>>>(
      (const _Float16*)Qw, (const _Float16*)Kw, (const _Float16*)Vtw, S3);

  // Wo -> bf16 into the now-dead Qw slot, then output projection
  conv1<<<512, 256, 0, stream>>>(Wo, Qw);
  gemm_bt<0><<<gg, 128, 0, stream>>>(S3, Qw, bo, d_out, 1.0f);
}

// Round 23
// 315.124 us; speedup vs baseline: 1.4660x; 1.0000x over previous
//
#include <hip/hip_runtime.h>
#include <stdint.h>

// CausalMultiHeadAttention — round 15.
// r22 post-mortem: item-fusion banked (322.6 -> 315.1; FETCH 37->25.7 MB as
// predicted) but attn only -4%: VALUBusy 50->65% — now VALU-bound on the
// softmax chain (MfmaUtil 19%). This round (ONE lever): T13 defer-max
// RESCALE_THRESHOLD=8 (log2 domain). Per tile, if the wave-uniform check
// __all(m0 - mrow <= 8) passes, keep the old running max: skip alpha exp2,
// the 16-mul o-rescale and lpart mul; P = exp2(st - m_old) <= 2^8 = 256,
// safe in fp16 (max 65504) and f32 accum. First live tile (mrow=-1e30)
// always takes the full path (alpha=0 exactly as before).
// GEMMs (all-gload16, bf16 W), conv4/conv1, epilogues: r22-measured,
// byte-identical.
// ws: Q | K | Vt (fp16) | {xb then O} (bf16) = 67.1 MB (proven size).

#define D_MODEL 1024
#define NHEAD   16
#define DK      64
#define BATCH   4
#define SEQ     2048
#define MTOT    (BATCH*SEQ)   // 8192

typedef unsigned short u16;
typedef unsigned int   u32;
typedef __bf16    bf16x8  __attribute__((ext_vector_type(8)));
typedef float     floatx4 __attribute__((ext_vector_type(4)));
typedef __fp16    fp16x2  __attribute__((ext_vector_type(2)));
typedef _Float16  half4_t __attribute__((ext_vector_type(4)));
typedef _Float16  half8_t __attribute__((ext_vector_type(8)));

// round-to-nearest-even f32 -> bf16 (epilogue only)
__device__ __forceinline__ u16 f2bf(float f){
  union { float f; u32 u; } c; c.f = f;
  u32 x = c.u;
  x += 0x7fffu + ((x >> 16) & 1u);
  return (u16)(x >> 16);
}
// f32 pair -> packed fp16 bits (RTZ, hardware packed cvt)
__device__ __forceinline__ u32 pkh(float a, float b){
  union { fp16x2 h; u32 u; } c; c.h = __builtin_amdgcn_cvt_pkrtz(a, b); return c.u;
}
// 8 fp32 -> 8 bf16 by truncation: one v_perm per pair
__device__ __forceinline__ uint4 pk8(const float* __restrict__ p){
  uint4 a = *(const uint4*)p;
  uint4 b = *(const uint4*)(p + 4);
  uint4 r;
  r.x = __builtin_amdgcn_perm(a.y, a.x, 0x07060302);
  r.y = __builtin_amdgcn_perm(a.w, a.z, 0x07060302);
  r.z = __builtin_amdgcn_perm(b.y, b.x, 0x07060302);
  r.w = __builtin_amdgcn_perm(b.w, b.z, 0x07060302);
  return r;
}
// async global->LDS, 16B per lane. LDS dest must be linear in lane order.
__device__ __forceinline__ void gload16(const void* g, void* l){
  __builtin_amdgcn_global_load_lds(
      (const __attribute__((address_space(1))) u32*)g,
      (__attribute__((address_space(3))) u32*)l, 16, 0, 0);
}

// ---------------------------------------------------------------------------
// Combined pre-pass: x (4096 blocks) + Wq/Wk/Wv (512 blocks each) -> bf16.
// ---------------------------------------------------------------------------
__global__ __launch_bounds__(256)
void conv4(const float* __restrict__ x,  u16* __restrict__ xb,
           const float* __restrict__ wq, const float* __restrict__ wk,
           const float* __restrict__ wv, u16* __restrict__ wb)
{
  const int b = blockIdx.x;
  const float* s; u16* d; size_t base;
  if (b < 4096)      { s = x;  d = xb;            base = (size_t)b * 2048; }
  else if (b < 4608) { s = wq; d = wb;            base = (size_t)(b-4096) * 2048; }
  else if (b < 5120) { s = wk; d = wb + (1u<<20); base = (size_t)(b-4608) * 2048; }
  else               { s = wv; d = wb + (2u<<20); base = (size_t)(b-5120) * 2048; }
  const size_t i = base + (size_t)threadIdx.x * 8;
  *(uint4*)(d + i) = pk8(s + i);
}

// single-matrix fp32 -> bf16 (Wo, post-attn, into the dead Qw slot)
__global__ __launch_bounds__(256)
void conv1(const float* __restrict__ s, u16* __restrict__ d)
{
  const size_t i = ((size_t)blockIdx.x * 256 + threadIdx.x) * 8;
  *(uint4*)(d + i) = pk8(s + i);
}

// ---------------------------------------------------------------------------
// GEMM (r21-measured, ~48 us): A MxK bf16, W NxK bf16, BOTH via gload16.
// 128x64 tile, BK=32, 128 thr = 2 waves stacked in m; each wave owns 64x64.
// Grid (64 m-tiles, 16 n-tiles) = 1024 blocks.
// ---------------------------------------------------------------------------
template<int MODE>
__global__ __launch_bounds__(128, 2)
void gemm_bt(const u16* __restrict__ A, const u16* __restrict__ W,
             const float* __restrict__ bias, void* __restrict__ outv,
             float scale)
{
  __shared__ __align__(16) u16 As[128*32];   // 8 KB
  __shared__ __align__(16) u16 Bs[64*32];    // 4 KB

  const int t    = threadIdx.x;              // 0..127
  const int m0   = blockIdx.x * 128;
  const int n0   = blockIdx.y * 64;
  const int wid  = t >> 6, lane = t & 63;
  const int wr   = wid;                      // wave row 0..1
  const int quad = lane >> 4, l15 = lane & 15;

  const int rS = t >> 2;                     // 0..31
  const int kS = (t & 3) * 8;

  const u16* Ap = A + (size_t)(m0 + rS)*D_MODEL + kS;
  const u16* Wp = W + (size_t)(n0 + rS)*D_MODEL + kS;

  floatx4 acc[4][4] = {};

  for (int k0 = 0; k0 < D_MODEL; k0 += 32) {
    __syncthreads();
    gload16(Ap + k0,               (char*)As + t*16);
    gload16(Ap + k0 + 32*D_MODEL,  (char*)As + 2048 + t*16);
    gload16(Ap + k0 + 64*D_MODEL,  (char*)As + 4096 + t*16);
    gload16(Ap + k0 + 96*D_MODEL,  (char*)As + 6144 + t*16);
    gload16(Wp + k0,               (char*)Bs + t*16);
    gload16(Wp + k0 + 32*D_MODEL,  (char*)Bs + 2048 + t*16);
    __syncthreads();

    bf16x8 af[4], bf[4];
#pragma unroll
    for (int i = 0; i < 4; ++i) {
      af[i] = *(const bf16x8*)&As[(wr*64 + i*16 + l15)*32 + quad*8];
      bf[i] = *(const bf16x8*)&Bs[(i*16 + l15)*32 + quad*8];
    }
#pragma unroll
    for (int mi = 0; mi < 4; ++mi)
#pragma unroll
      for (int nj = 0; nj < 4; ++nj) {
        if (MODE == 2)
          acc[mi][nj] = __builtin_amdgcn_mfma_f32_16x16x32_bf16(af[mi], bf[nj], acc[mi][nj], 0, 0, 0);
        else
          acc[mi][nj] = __builtin_amdgcn_mfma_f32_16x16x32_bf16(bf[nj], af[mi], acc[mi][nj], 0, 0, 0);
      }
  }

  if (MODE != 2) {
#pragma unroll
    for (int nj = 0; nj < 4; ++nj) {
      const int nb = n0 + nj*16 + quad*4;
      const float4 b4 = *(const float4*)(bias + nb);
#pragma unroll
      for (int mi = 0; mi < 4; ++mi) {
        const int m = m0 + wr*64 + mi*16 + l15;
        floatx4 d = acc[mi][nj];
        const float v0 = (d[0]+b4.x)*scale, v1 = (d[1]+b4.y)*scale;
        const float v2 = (d[2]+b4.z)*scale, v3 = (d[3]+b4.w)*scale;
        if (MODE == 0) {
          float4 s4 = make_float4(v0, v1, v2, v3);
          *(float4*)((float*)outv + (size_t)m*D_MODEL + nb) = s4;
        } else {
          const int b = m >> 11, s = m & 2047, h = nb >> 6, dd = nb & 63;
          u16* dst = (u16*)outv + ((((size_t)b*NHEAD + h)*SEQ + s) << 6) + dd;
          *(uint2*)dst = make_uint2(pkh(v0, v1), pkh(v2, v3));
        }
      }
    }
  } else {
#pragma unroll
    for (int nj = 0; nj < 4; ++nj) {
      const int n  = n0 + nj*16 + l15;
      const float bvv = bias[n];
      const int h = n >> 6, dd = n & 63;
#pragma unroll
      for (int mi = 0; mi < 4; ++mi) {
        const int mb = m0 + wr*64 + mi*16 + quad*4;
        const int b = mb >> 11, s = mb & 2047;
        floatx4 d = acc[mi][nj];
        u16* dst = (u16*)outv + (((size_t)b*NHEAD + h)*DK + dd)*SEQ + s;
        *(uint2*)dst = make_uint2(pkh(d[0]+bvv, d[1]+bvv), pkh(d[2]+bvv, d[3]+bvv));
      }
    }
  }
}

// ---------------------------------------------------------------------------
// Per-tile attention compute (one item) with T13 defer-max (THR=8, log2
// domain): when the wave-uniform check passes, keep the old running max and
// skip the alpha exp2 + 16-mul o-rescale + lpart mul. P <= 2^8, fp16-safe.
// ---------------------------------------------------------------------------
__device__ __forceinline__ void attn_tile(
    const _Float16 (*Ks)[72], const _Float16 (*Vs)[72],
    int j0, int qb, int query, int quad, int l15,
    const half8_t* qf, float& mrow, float& lpart, floatx4* o)
{
  const int ktmax = ((qb + 15 - j0) >> 4) + 1;     // 1..4+, wave-uniform

  floatx4 st[4];
#pragma unroll
  for (int kt = 0; kt < 4; ++kt) {
    if (kt < ktmax) {
      half8_t a0 = *(const half8_t*)&Ks[kt*16 + l15][quad*8];
      half8_t a1 = *(const half8_t*)&Ks[kt*16 + l15][32 + quad*8];
      floatx4 s = {};
      s = __builtin_amdgcn_mfma_f32_16x16x32_f16(a0, qf[0], s, 0, 0, 0);
      s = __builtin_amdgcn_mfma_f32_16x16x32_f16(a1, qf[1], s, 0, 0, 0);
      st[kt] = s;
    }
  }
#pragma unroll
  for (int kt = 0; kt < 4; ++kt) {
    if (kt < ktmax && j0 + kt*16 + 15 > qb) {
#pragma unroll
      for (int r = 0; r < 4; ++r)
        if (j0 + kt*16 + quad*4 + r > query) st[kt][r] = -1e30f;
    }
  }
  float m0 = -1e30f;
#pragma unroll
  for (int kt = 0; kt < 4; ++kt)
    if (kt < ktmax)
      m0 = fmaxf(m0, fmaxf(fmaxf(st[kt][0], st[kt][1]), fmaxf(st[kt][2], st[kt][3])));
  m0 = fmaxf(m0, __shfl_xor(m0, 16));
  m0 = fmaxf(m0, __shfl_xor(m0, 32));

  // ---- T13 defer-max: skip rescale when max growth <= 8 (wave-uniform)
  if (!__all(m0 - mrow <= 8.0f)) {
    const float mn    = fmaxf(mrow, m0);
    const float alpha = exp2f(mrow - mn);          // 0 on first live tile
    mrow = mn;
    lpart *= alpha;
#pragma unroll
    for (int dt = 0; dt < 4; ++dt) {
      o[dt][0] *= alpha; o[dt][1] *= alpha; o[dt][2] *= alpha; o[dt][3] *= alpha;
    }
  }
  half4_t pf[4];
#pragma unroll
  for (int kt = 0; kt < 4; ++kt) {
    if (kt < ktmax) {
      const float p0 = exp2f(st[kt][0] - mrow), p1 = exp2f(st[kt][1] - mrow);
      const float p2 = exp2f(st[kt][2] - mrow), p3 = exp2f(st[kt][3] - mrow);
      lpart += (p0 + p1) + (p2 + p3);
      union { half4_t h; uint2 u; } pc;
      pc.u = make_uint2(pkh(p0, p1), pkh(p2, p3));
      pf[kt] = pc.h;
    }
  }
#pragma unroll
  for (int dt = 0; dt < 4; ++dt)
#pragma unroll
    for (int kt = 0; kt < 4; ++kt) {
      if (kt < ktmax) {
        half4_t vf = *(const half4_t*)&Vs[dt*16 + l15][kt*16 + quad*4];
        o[dt] = __builtin_amdgcn_mfma_f32_16x16x16f16(vf, pf[kt], o[dt], 0, 0, 0);
      }
    }
}

// ---------------------------------------------------------------------------
// MFMA flash attention, ITEM-FUSED (r22-measured structure). Grid
// (64 bh, 16 pid), 256 thr = 4 waves. Block pid owns query-blocks
// {31-pid (heavy), pid}; one staging loop serves both items.
// XCD locality (bh%8) and per-query deferred-l epilogue unchanged.
// ---------------------------------------------------------------------------
__global__ __launch_bounds__(256, 4)
void attn_fwd(const _Float16* __restrict__ Q, const _Float16* __restrict__ K,
              const _Float16* __restrict__ Vt, u16* __restrict__ O)
{
  __shared__ __align__(16) _Float16 Ks[64][72];
  __shared__ __align__(16) _Float16 Vs[64][72];

  const int bh   = blockIdx.x;              // 0..63  (bh%8 = home XCD)
  const int pid  = blockIdx.y;              // 0..15
  const int t    = threadIdx.x;
  const int w    = t >> 6, lane = t & 63;
  const int quad = lane >> 4, l15 = lane & 15;
  const int sr = t >> 3, sc8 = (t & 7) * 8;
  const _Float16* Kb = K  + (size_t)bh * SEQ * DK;
  const _Float16* Vb = Vt + (size_t)bh * DK * SEQ;

  const int rblk0 = 31 - pid;               // heavy item
  const int rblk1 = pid;                    // light item (subset range)
  const int qb0 = rblk0*64 + w*16, q0 = qb0 + l15;
  const int qb1 = rblk1*64 + w*16, q1 = qb1 + l15;

  half8_t qf0[2], qf1[2];
  {
    const _Float16* Qp0 = Q + ((size_t)bh * SEQ + q0) * DK + quad * 8;
    qf0[0] = *(const half8_t*)(Qp0);
    qf0[1] = *(const half8_t*)(Qp0 + 32);
    const _Float16* Qp1 = Q + ((size_t)bh * SEQ + q1) * DK + quad * 8;
    qf1[0] = *(const half8_t*)(Qp1);
    qf1[1] = *(const half8_t*)(Qp1 + 32);
  }

  float mrow0 = -1e30f, lpart0 = 0.f;
  float mrow1 = -1e30f, lpart1 = 0.f;
  floatx4 o0[4] = {};
  floatx4 o1[4] = {};

  const int jend = rblk0*64 + 64;           // item0's range covers item1's
#pragma unroll 1
  for (int j0 = 0; j0 < jend; j0 += 64) {
    __syncthreads();
    *(uint4*)&Ks[sr     ][sc8] = *(const uint4*)(Kb + (size_t)(j0 + sr     )*DK + sc8);
    *(uint4*)&Ks[sr + 32][sc8] = *(const uint4*)(Kb + (size_t)(j0 + sr + 32)*DK + sc8);
    *(uint4*)&Vs[sr     ][sc8] = *(const uint4*)(Vb + (size_t)(sr     )*SEQ + j0 + sc8);
    *(uint4*)&Vs[sr + 32][sc8] = *(const uint4*)(Vb + (size_t)(sr + 32)*SEQ + j0 + sc8);
    __syncthreads();
    if (j0 <= qb0 + 15)
      attn_tile(Ks, Vs, j0, qb0, q0, quad, l15, qf0, mrow0, lpart0, o0);
    if (j0 <= qb1 + 15)
      attn_tile(Ks, Vs, j0, qb1, q1, quad, l15, qf1, mrow1, lpart1, o1);
  }

  // ---- epilogue: deferred l reduction, O bf16 [B,S,D], both items
  const int b = bh >> 4, h = bh & 15;
  {
    float l = lpart0;
    l += __shfl_xor(l, 16);
    l += __shfl_xor(l, 32);
    const float inv = 1.0f / l;
    u16* Op = O + ((size_t)(b * SEQ + q0)) * D_MODEL + h * DK + quad * 4;
#pragma unroll
    for (int dt = 0; dt < 4; ++dt) {
      u32 lo = ((u32)f2bf(o0[dt][1] * inv) << 16) | f2bf(o0[dt][0] * inv);
      u32 hi = ((u32)f2bf(o0[dt][3] * inv) << 16) | f2bf(o0[dt][2] * inv);
      *(uint2*)(Op + dt * 16) = make_uint2(lo, hi);
    }
  }
  {
    float l = lpart1;
    l += __shfl_xor(l, 16);
    l += __shfl_xor(l, 32);
    const float inv = 1.0f / l;
    u16* Op = O + ((size_t)(b * SEQ + q1)) * D_MODEL + h * DK + quad * 4;
#pragma unroll
    for (int dt = 0; dt < 4; ++dt) {
      u32 lo = ((u32)f2bf(o1[dt][1] * inv) << 16) | f2bf(o1[dt][0] * inv);
      u32 hi = ((u32)f2bf(o1[dt][3] * inv) << 16) | f2bf(o1[dt][2] * inv);
      *(uint2*)(Op + dt * 16) = make_uint2(lo, hi);
    }
  }
}

// ---------------------------------------------------------------------------
extern "C" void kernel_launch(void* const* d_in, const int* in_sizes, int n_in,
                              void* d_out, int out_size, void* d_ws, size_t ws_size,
                              hipStream_t stream)
{
  const float* x  = (const float*)d_in[0];
  const float* Wq = (const float*)d_in[1];
  const float* bq = (const float*)d_in[2];
  const float* Wk = (const float*)d_in[3];
  const float* bk = (const float*)d_in[4];
  const float* Wv = (const float*)d_in[5];
  const float* bv = (const float*)d_in[6];
  const float* Wo = (const float*)d_in[7];
  const float* bo = (const float*)d_in[8];

  const size_t tsz = (size_t)MTOT * D_MODEL;
  u16* Qw  = (u16*)d_ws;
  u16* Kw  = Qw + tsz;
  u16* Vtw = Kw + tsz;
  u16* S3  = Vtw + tsz;      // shared slot: xb (pre-attn) then O (post-attn)
  u16* WB  = (u16*)d_out;    // d_out as scratch: Wq|Wk|Wv bf16 (6 MB),
                             // dead until gemm_out overwrites it at the end.

  // x -> S3, Wq/Wk/Wv -> d_out scratch (all pk8 truncation)
  conv4<<<4096 + 3*512, 256, 0, stream>>>(x, S3, Wq, Wk, Wv, WB);

  dim3 gg(MTOT/128, D_MODEL/64);               // (64 m-tiles, 16 n-tiles)
  // Q scale = 1/sqrt(dk) * log2(e): softmax runs in log2 domain
  gemm_bt<1><<<gg, 128, 0, stream>>>(S3, WB,            bq, Qw,  0.18033688f);
  gemm_bt<1><<<gg, 128, 0, stream>>>(S3, WB + (1u<<20), bk, Kw,  1.0f);
  gemm_bt<2><<<gg, 128, 0, stream>>>(S3, WB + (2u<<20), bv, Vtw, 1.0f);

  attn_fwd<<<dim3(BATCH*NHEAD, SEQ/128), 256, 0, stream>>>(
      (const _Float16*)Qw, (const _Float16*)Kw, (const _Float16*)Vtw, S3);

  // Wo -> bf16 into the now-dead Qw slot, then output projection
  conv1<<<512, 256, 0, stream>>>(Wo, Qw);
  gemm_bt<0><<<gg, 128, 0, stream>>>(S3, Qw, bo, d_out, 1.0f);
}